// Round 15
// baseline (53.538 us; speedup 1.0000x reference)
//
#include <hip/hip_runtime.h>
#include <hip/hip_fp16.h>
#include <math.h>

#define V   50000
#define DIM 128
#define BB  512
#define LQ  30
#define RD  200
#define KN  21

typedef __attribute__((ext_vector_type(8))) _Float16 f16x8;  // 8 f16 = 4 VGPRs
typedef __attribute__((ext_vector_type(4))) float f32x4;
typedef __attribute__((ext_vector_type(2))) float f32x2;     // -> v_pk_*_f32

#if __has_builtin(__builtin_amdgcn_exp2f)
#define EXP2F(x) __builtin_amdgcn_exp2f(x)
#else
#define EXP2F(x) __expf((x) * 0.69314718f)
#endif

#define ALPHA 72.1347520f       // 50 * log2(e)
#define E10   22026.4657948f    // 2^(0.2*ALPHA) = e^10

static __device__ __forceinline__ f16x8 as_hfrag(int4 v) {
    return __builtin_bit_cast(f16x8, v);
}
static __device__ __forceinline__ unsigned pk2h(float a, float b) {
    return __builtin_bit_cast(unsigned, __builtin_amdgcn_cvt_pkrtz(a, b));
}
static __device__ __forceinline__ unsigned hscale(unsigned u, __half2 s) {
    return __builtin_bit_cast(unsigned, __hmul2(__builtin_bit_cast(__half2, u), s));
}

// ---- split doc gather: issue loads early (T14), pack/normalize later ----
static __device__ __forceinline__ void issue_row_loads(const float* __restrict__ rowp,
                                                       int g, float4* raw) {
#pragma unroll
    for (int ks = 0; ks < 4; ++ks) {
        const float4* p = reinterpret_cast<const float4*>(rowp + ks * 32 + g * 8);
        raw[2 * ks]     = p[0];
        raw[2 * ks + 1] = p[1];
    }
}
// 4 independent fma chains for ss; RTZ-pack, cross-g reduce, f16 scale.
static __device__ __forceinline__ void pack_row(const float4* raw, int4* f) {
    float c0 = 0.f, c1 = 0.f, c2 = 0.f, c3 = 0.f;
    {
        float4 a = raw[0], b = raw[1];
        c0 = fmaf(a.x, a.x, fmaf(a.y, a.y, c0)); c1 = fmaf(a.z, a.z, fmaf(a.w, a.w, c1));
        c2 = fmaf(b.x, b.x, fmaf(b.y, b.y, c2)); c3 = fmaf(b.z, b.z, fmaf(b.w, b.w, c3));
        f[0].x = (int)pk2h(a.x, a.y); f[0].y = (int)pk2h(a.z, a.w);
        f[0].z = (int)pk2h(b.x, b.y); f[0].w = (int)pk2h(b.z, b.w);
    }
    {
        float4 a = raw[2], b = raw[3];
        c0 = fmaf(a.x, a.x, fmaf(a.y, a.y, c0)); c1 = fmaf(a.z, a.z, fmaf(a.w, a.w, c1));
        c2 = fmaf(b.x, b.x, fmaf(b.y, b.y, c2)); c3 = fmaf(b.z, b.z, fmaf(b.w, b.w, c3));
        f[1].x = (int)pk2h(a.x, a.y); f[1].y = (int)pk2h(a.z, a.w);
        f[1].z = (int)pk2h(b.x, b.y); f[1].w = (int)pk2h(b.z, b.w);
    }
    {
        float4 a = raw[4], b = raw[5];
        c0 = fmaf(a.x, a.x, fmaf(a.y, a.y, c0)); c1 = fmaf(a.z, a.z, fmaf(a.w, a.w, c1));
        c2 = fmaf(b.x, b.x, fmaf(b.y, b.y, c2)); c3 = fmaf(b.z, b.z, fmaf(b.w, b.w, c3));
        f[2].x = (int)pk2h(a.x, a.y); f[2].y = (int)pk2h(a.z, a.w);
        f[2].z = (int)pk2h(b.x, b.y); f[2].w = (int)pk2h(b.z, b.w);
    }
    {
        float4 a = raw[6], b = raw[7];
        c0 = fmaf(a.x, a.x, fmaf(a.y, a.y, c0)); c1 = fmaf(a.z, a.z, fmaf(a.w, a.w, c1));
        c2 = fmaf(b.x, b.x, fmaf(b.y, b.y, c2)); c3 = fmaf(b.z, b.z, fmaf(b.w, b.w, c3));
        f[3].x = (int)pk2h(a.x, a.y); f[3].y = (int)pk2h(a.z, a.w);
        f[3].z = (int)pk2h(b.x, b.y); f[3].w = (int)pk2h(b.z, b.w);
    }
    float ss = (c0 + c1) + (c2 + c3);
    ss += __shfl_xor(ss, 16);
    ss += __shfl_xor(ss, 32);
    const float inv = rsqrtf(fmaxf(ss, 1e-24f));
    const __half2 h2 = __float2half2_rn(inv);
#pragma unroll
    for (int ks = 0; ks < 4; ++ks) {
        f[ks].x = (int)hscale((unsigned)f[ks].x, h2);
        f[ks].y = (int)hscale((unsigned)f[ks].y, h2);
        f[ks].z = (int)hscale((unsigned)f[ks].z, h2);
        f[ks].w = (int)hscale((unsigned)f[ks].w, h2);
    }
}

// Two-leg geometric Gaussian bank (verified R6..R14), packed f32x2
// (x = leg A, kernels 0..9 center mu=-0.5; y = leg B, 10..19 center +0.5),
// 4 independent t*u chains, tree summation. B_j folded in at combine.
// Exact kernel (mu=1, sigma=1e-3) = integer token equality count.
static __device__ __forceinline__ void bank4_pk(f32x4 pv, int4 dt, int qt,
                                                f32x2* ks2, float& cnt) {
    const float mv[4] = {pv[0], pv[1], pv[2], pv[3]};
    const int   dv[4] = {dt.x, dt.y, dt.z, dt.w};
    f32x2 t[4], u[4];
#pragma unroll
    for (int i = 0; i < 4; ++i) {
        float m  = mv[i];
        float dA = m + 0.5f, dB = m - 0.5f;
        float tA = EXP2F(-ALPHA * dA * (dA + 0.9f));   // leg A start (k=0)
        float tB = EXP2F(-ALPHA * dB * (dB + 0.9f));   // leg B start (k=10)
        float uB = EXP2F(14.4269504f * dB);            // 2^(0.2*ALPHA*dB)
        float uA = uB * E10;
        t[i] = f32x2{tA, tB};
        u[i] = f32x2{uA, uB};
        cnt += (dv[i] == qt) ? 1.0f : 0.0f;
    }
#pragma unroll
    for (int k = 0; k < 10; ++k) {
        ks2[k] += (t[0] + t[1]) + (t[2] + t[3]);       // tree: short dep chains
        t[0] *= u[0]; t[1] *= u[1]; t[2] *= u[2]; t[3] *= u[3];
    }
}

// ------------- kernel: fused-norm swapped-operand KNRM, pipelined strips -------------
// 1024 blocks (pair*b) x 256 thr (4 waves). 13 strips of 16 cols round-robin:
// wave w runs strips {w, w+4, w+8} (+strip 12 for w=0). mfma(A=D, B=Q):
// C row = dcol (g*4+j), C col = qrow (r); bank reads accumulators directly.
// Doc loads for strip s+1 issued before MFMA+bank of strip s (T14 pipeline).
__global__ __launch_bounds__(256, 4) void knrm_main(
    const float* __restrict__ emb, const float* __restrict__ W,
    const int* __restrict__ q1, const int* __restrict__ d1,
    const int* __restrict__ q2, const int* __restrict__ d2,
    float* __restrict__ logits)
{
    __shared__ int sQtok[32];
    __shared__ __align__(16) int sDtok[256];
    __shared__ int4 sQ[32][16];                    // 32 rows x 256B f16, swizzled
    __shared__ float kred[4][32][KN];              // 10752 B

    const int pb = blockIdx.x;
    const int pair = pb >> 9, b = pb & 511;
    const int* qind = (pair ? q2 : q1) + b * LQ;
    const int* dind = (pair ? d2 : d1) + b * RD;

    const int tid = threadIdx.x;
    const int lane = tid & 63, w = tid >> 6;
    const int r = lane & 15, g = lane >> 4;

    if (tid < 32) sQtok[tid] = (tid < LQ) ? qind[tid] : -2;
    // padded entries get clamped token; padded quads never reach the bank
    sDtok[tid] = dind[tid < RD ? tid : RD - 1];

    // ---- cooperative Q staging: row = tid>>3, 16 elems per thread ----
    {
        const int row = tid >> 3, seg = tid & 7;
        const int qi = qind[row < LQ ? row : LQ - 1];
        const float4* p = reinterpret_cast<const float4*>(emb + (size_t)qi * DIM + seg * 16);
        float4 v0 = p[0], v1 = p[1], v2 = p[2], v3 = p[3];
        float s0 = 0.f, s1 = 0.f, s2 = 0.f, s3 = 0.f;
        s0 = fmaf(v0.x, v0.x, fmaf(v0.y, v0.y, s0)); s1 = fmaf(v0.z, v0.z, fmaf(v0.w, v0.w, s1));
        s2 = fmaf(v1.x, v1.x, fmaf(v1.y, v1.y, s2)); s3 = fmaf(v1.z, v1.z, fmaf(v1.w, v1.w, s3));
        s0 = fmaf(v2.x, v2.x, fmaf(v2.y, v2.y, s0)); s1 = fmaf(v2.z, v2.z, fmaf(v2.w, v2.w, s1));
        s2 = fmaf(v3.x, v3.x, fmaf(v3.y, v3.y, s2)); s3 = fmaf(v3.z, v3.z, fmaf(v3.w, v3.w, s3));
        float ss = (s0 + s1) + (s2 + s3);
        ss += __shfl_xor(ss, 1);
        ss += __shfl_xor(ss, 2);
        ss += __shfl_xor(ss, 4);
        const float inv = rsqrtf(fmaxf(ss, 1e-24f));
        int4 t0, t1;
        t0.x = (int)pk2h(v0.x * inv, v0.y * inv);
        t0.y = (int)pk2h(v0.z * inv, v0.w * inv);
        t0.z = (int)pk2h(v1.x * inv, v1.y * inv);
        t0.w = (int)pk2h(v1.z * inv, v1.w * inv);
        t1.x = (int)pk2h(v2.x * inv, v2.y * inv);
        t1.y = (int)pk2h(v2.z * inv, v2.w * inv);
        t1.z = (int)pk2h(v3.x * inv, v3.y * inv);
        t1.w = (int)pk2h(v3.z * inv, v3.w * inv);
        const int rw = row & 15;                   // XOR-swizzle (rule 21: both sides)
        sQ[row][(2 * seg) ^ rw]     = t0;
        sQ[row][(2 * seg + 1) ^ rw] = t1;
    }
    __syncthreads();                               // tokens + sQ ready (only barrier)

    const int qt0 = sQtok[r], qt1 = sQtok[16 + r];
    const int4* sDtok4 = (const int4*)sDtok;

    f32x2 ks0[10], ks1[10];
#pragma unroll
    for (int k = 0; k < 10; ++k) { ks0[k] = f32x2{0.f, 0.f}; ks1[k] = f32x2{0.f, 0.f}; }
    float cnt0 = 0.0f, cnt1 = 0.0f;

    // MFMA + bank on a packed strip (Q frags re-read from swizzled LDS)
    auto do_strip = [&](const int4* df, int sbase) {
        f32x4 acc0 = {0.f, 0.f, 0.f, 0.f}, acc1 = {0.f, 0.f, 0.f, 0.f};
#pragma unroll
        for (int ks = 0; ks < 4; ++ks) {
            f16x8 fd = as_hfrag(df[ks]);
            acc0 = __builtin_amdgcn_mfma_f32_16x16x32_f16(fd, as_hfrag(sQ[r][(ks * 4 + g) ^ r]), acc0, 0, 0, 0);
            acc1 = __builtin_amdgcn_mfma_f32_16x16x32_f16(fd, as_hfrag(sQ[16 + r][(ks * 4 + g) ^ r]), acc1, 0, 0, 0);
        }
        if (sbase + g * 4 < RD) {                  // RD%4==0 -> quad all-or-none
            const int4 dt = sDtok4[(sbase >> 2) + g];
            bank4_pk(acc0, dt, qt0, ks0, cnt0);
            bank4_pk(acc1, dt, qt1, ks1, cnt1);
        }
    };

    // ---- pipelined strip schedule: wave w -> strips w, w+4, w+8 (+12 if w==0) ----
    {
        float4 raw[8];
        int4 df[4];
        const int sb0 = w * 16, sb1 = (w + 4) * 16, sb2 = (w + 8) * 16;

        issue_row_loads(emb + (size_t)sDtok[sb0 + r] * DIM, g, raw);

        pack_row(raw, df);
        issue_row_loads(emb + (size_t)sDtok[sb1 + r] * DIM, g, raw);   // prefetch s1
        do_strip(df, sb0);

        pack_row(raw, df);
        issue_row_loads(emb + (size_t)sDtok[sb2 + r] * DIM, g, raw);   // prefetch s2
        do_strip(df, sb1);

        pack_row(raw, df);
        if (w == 0)
            issue_row_loads(emb + (size_t)sDtok[192 + r] * DIM, g, raw); // prefetch s3
        do_strip(df, sb2);

        if (w == 0) {
            pack_row(raw, df);
            do_strip(df, 192);                     // strip 12: quads >=200 masked
        }
    }

    // ---- reduce over g (xor16, xor32), writer lanes g==0 ----
#pragma unroll
    for (int k = 0; k < 10; ++k) {
        float a0 = ks0[k].x, b0 = ks0[k].y, a1 = ks1[k].x, b1 = ks1[k].y;
        a0 += __shfl_xor(a0, 16); a0 += __shfl_xor(a0, 32);
        b0 += __shfl_xor(b0, 16); b0 += __shfl_xor(b0, 32);
        a1 += __shfl_xor(a1, 16); a1 += __shfl_xor(a1, 32);
        b1 += __shfl_xor(b1, 16); b1 += __shfl_xor(b1, 32);
        ks0[k] = f32x2{a0, b0};
        ks1[k] = f32x2{a1, b1};
    }
    cnt0 += __shfl_xor(cnt0, 16); cnt0 += __shfl_xor(cnt0, 32);
    cnt1 += __shfl_xor(cnt1, 16); cnt1 += __shfl_xor(cnt1, 32);

    if (lane < 16) {
        float* k0 = &kred[w][r][0];
        float* k1 = &kred[w][16 + r][0];
#pragma unroll
        for (int k = 0; k < 10; ++k) {
            k0[k] = ks0[k].x;  k0[10 + k] = ks0[k].y;
            k1[k] = ks1[k].x;  k1[10 + k] = ks1[k].y;
        }
        k0[20] = cnt0;
        k1[20] = cnt1;
    }
    __syncthreads();

    // ---- in-block combine: B_j scale, log1p, W-dot, row reduce -> logit ----
    if (tid < 64) {
        float part = 0.0f;
        if (tid < LQ) {
#pragma unroll
            for (int k = 0; k < KN; ++k) {
                float s = kred[0][tid][k] + kred[1][tid][k]
                        + kred[2][tid][k] + kred[3][tid][k];
                float sc = 1.0f;
                if (k < 20) {
                    float j = (float)((k < 10) ? k : k - 10) - 4.5f;
                    sc = EXP2F(-0.721347520f * j * j);   // B_j (compile-time)
                }
                part += W[k] * log1pf(sc * s);
            }
        }
        part += __shfl_xor(part, 1);
        part += __shfl_xor(part, 2);
        part += __shfl_xor(part, 4);
        part += __shfl_xor(part, 8);
        part += __shfl_xor(part, 16);
        part += __shfl_xor(part, 32);
        if (tid == 0) logits[pair * BB + b] = part;   // bias cancels in diff
    }
}

// ------------- kernel 2: sigmoid of logit difference -------------
__global__ void knrm_final(const float* __restrict__ logits, float* __restrict__ out) {
    int i = blockIdx.x * blockDim.x + threadIdx.x;
    if (i < BB) {
        float x = logits[i] - logits[BB + i];
        out[i] = 1.0f / (1.0f + expf(-x));
    }
}

extern "C" void kernel_launch(void* const* d_in, const int* in_sizes, int n_in,
                              void* d_out, int out_size, void* d_ws, size_t ws_size,
                              hipStream_t stream) {
    const float* emb = (const float*)d_in[0];
    const float* W   = (const float*)d_in[1];
    const int* q1    = (const int*)d_in[3];
    const int* dd1   = (const int*)d_in[4];
    const int* q2    = (const int*)d_in[5];
    const int* dd2   = (const int*)d_in[6];

    float* logits = (float*)d_ws;                    // 1024 floats

    knrm_main<<<1024, 256, 0, stream>>>(emb, W, q1, dd1, q2, dd2, logits);
    knrm_final<<<2, 256, 0, stream>>>(logits, (float*)d_out);
}

// Round 16
// 51.429 us; speedup vs baseline: 1.0410x; 1.0410x over previous
//
#include <hip/hip_runtime.h>
#include <hip/hip_fp16.h>
#include <math.h>

#define V   50000
#define DIM 128
#define BB  512
#define LQ  30
#define RD  200
#define KN  21

typedef __attribute__((ext_vector_type(8))) _Float16 f16x8;  // 8 f16 = 4 VGPRs
typedef __attribute__((ext_vector_type(4))) float f32x4;
typedef __attribute__((ext_vector_type(2))) float f32x2;     // -> v_pk_*_f32

#if __has_builtin(__builtin_amdgcn_exp2f)
#define EXP2F(x) __builtin_amdgcn_exp2f(x)
#else
#define EXP2F(x) __expf((x) * 0.69314718f)
#endif

#define ALPHA 72.1347520f       // 50 * log2(e)
#define E10   22026.4657948f    // 2^(0.2*ALPHA) = e^10

static __device__ __forceinline__ f16x8 as_hfrag(int4 v) {
    return __builtin_bit_cast(f16x8, v);
}
static __device__ __forceinline__ unsigned pk2h(float a, float b) {
    return __builtin_bit_cast(unsigned, __builtin_amdgcn_cvt_pkrtz(a, b));
}
static __device__ __forceinline__ unsigned hscale(unsigned u, __half2 s) {
    return __builtin_bit_cast(unsigned, __hmul2(__builtin_bit_cast(__half2, u), s));
}

// Two-leg geometric Gaussian bank (verified R6..R14), packed f32x2
// (x = leg A, kernels 0..9 center mu=-0.5; y = leg B, 10..19 center +0.5),
// 4 independent t*u chains, tree summation. B_j folded in at combine.
// Exact kernel (mu=1, sigma=1e-3) = integer token equality count.
static __device__ __forceinline__ void bank4_pk(f32x4 pv, int4 dt, int qt,
                                                f32x2* ks2, float& cnt) {
    const float mv[4] = {pv[0], pv[1], pv[2], pv[3]};
    const int   dv[4] = {dt.x, dt.y, dt.z, dt.w};
    f32x2 t[4], u[4];
#pragma unroll
    for (int i = 0; i < 4; ++i) {
        float m  = mv[i];
        float dA = m + 0.5f, dB = m - 0.5f;
        float tA = EXP2F(-ALPHA * dA * (dA + 0.9f));   // leg A start (k=0)
        float tB = EXP2F(-ALPHA * dB * (dB + 0.9f));   // leg B start (k=10)
        float uB = EXP2F(14.4269504f * dB);            // 2^(0.2*ALPHA*dB)
        float uA = uB * E10;
        t[i] = f32x2{tA, tB};
        u[i] = f32x2{uA, uB};
        cnt += (dv[i] == qt) ? 1.0f : 0.0f;
    }
#pragma unroll
    for (int k = 0; k < 10; ++k) {
        ks2[k] += (t[0] + t[1]) + (t[2] + t[3]);       // tree: short dep chains
        t[0] *= u[0]; t[1] *= u[1]; t[2] *= u[2]; t[3] *= u[3];
    }
}

// ---- spill-proof pipeline macros: only named registers, no arrays/lambdas ----
#define LOADROW(sb) do {                                                      \
    const float* rp_ = emb + (size_t)sDtok[(sb) + r] * DIM + g * 8;           \
    r0 = *(const float4*)(rp_);        r1 = *(const float4*)(rp_ + 4);        \
    r2 = *(const float4*)(rp_ + 32);   r3 = *(const float4*)(rp_ + 36);       \
    r4 = *(const float4*)(rp_ + 64);   r5 = *(const float4*)(rp_ + 68);       \
    r6 = *(const float4*)(rp_ + 96);   r7 = *(const float4*)(rp_ + 100);      \
} while (0)

#define PACKROW() do {                                                        \
    float c0_, c1_, c2_, c3_;                                                 \
    c0_ = fmaf(r0.x,r0.x,fmaf(r0.y,r0.y,0.f)); c1_ = fmaf(r0.z,r0.z,fmaf(r0.w,r0.w,0.f)); \
    c2_ = fmaf(r1.x,r1.x,fmaf(r1.y,r1.y,0.f)); c3_ = fmaf(r1.z,r1.z,fmaf(r1.w,r1.w,0.f)); \
    c0_ = fmaf(r2.x,r2.x,fmaf(r2.y,r2.y,c0_)); c1_ = fmaf(r2.z,r2.z,fmaf(r2.w,r2.w,c1_)); \
    c2_ = fmaf(r3.x,r3.x,fmaf(r3.y,r3.y,c2_)); c3_ = fmaf(r3.z,r3.z,fmaf(r3.w,r3.w,c3_)); \
    c0_ = fmaf(r4.x,r4.x,fmaf(r4.y,r4.y,c0_)); c1_ = fmaf(r4.z,r4.z,fmaf(r4.w,r4.w,c1_)); \
    c2_ = fmaf(r5.x,r5.x,fmaf(r5.y,r5.y,c2_)); c3_ = fmaf(r5.z,r5.z,fmaf(r5.w,r5.w,c3_)); \
    c0_ = fmaf(r6.x,r6.x,fmaf(r6.y,r6.y,c0_)); c1_ = fmaf(r6.z,r6.z,fmaf(r6.w,r6.w,c1_)); \
    c2_ = fmaf(r7.x,r7.x,fmaf(r7.y,r7.y,c2_)); c3_ = fmaf(r7.z,r7.z,fmaf(r7.w,r7.w,c3_)); \
    float ss_ = (c0_ + c1_) + (c2_ + c3_);                                    \
    ss_ += __shfl_xor(ss_, 16);  ss_ += __shfl_xor(ss_, 32);                  \
    const float inv_ = rsqrtf(fmaxf(ss_, 1e-24f));                            \
    const __half2 h2_ = __float2half2_rn(inv_);                               \
    d0.x = (int)hscale(pk2h(r0.x, r0.y), h2_); d0.y = (int)hscale(pk2h(r0.z, r0.w), h2_); \
    d0.z = (int)hscale(pk2h(r1.x, r1.y), h2_); d0.w = (int)hscale(pk2h(r1.z, r1.w), h2_); \
    d1.x = (int)hscale(pk2h(r2.x, r2.y), h2_); d1.y = (int)hscale(pk2h(r2.z, r2.w), h2_); \
    d1.z = (int)hscale(pk2h(r3.x, r3.y), h2_); d1.w = (int)hscale(pk2h(r3.z, r3.w), h2_); \
    d2.x = (int)hscale(pk2h(r4.x, r4.y), h2_); d2.y = (int)hscale(pk2h(r4.z, r4.w), h2_); \
    d2.z = (int)hscale(pk2h(r5.x, r5.y), h2_); d2.w = (int)hscale(pk2h(r5.z, r5.w), h2_); \
    d3.x = (int)hscale(pk2h(r6.x, r6.y), h2_); d3.y = (int)hscale(pk2h(r6.z, r6.w), h2_); \
    d3.z = (int)hscale(pk2h(r7.x, r7.y), h2_); d3.w = (int)hscale(pk2h(r7.z, r7.w), h2_); \
} while (0)

#define DOSTRIP(sb) do {                                                      \
    f32x4 acc0_ = {0.f,0.f,0.f,0.f}, acc1_ = {0.f,0.f,0.f,0.f};               \
    { f16x8 fd_ = as_hfrag(d0);                                               \
      acc0_ = __builtin_amdgcn_mfma_f32_16x16x32_f16(fd_, as_hfrag(sQ[r][(0+g)^r]), acc0_,0,0,0);      \
      acc1_ = __builtin_amdgcn_mfma_f32_16x16x32_f16(fd_, as_hfrag(sQ[16+r][(0+g)^r]), acc1_,0,0,0); } \
    { f16x8 fd_ = as_hfrag(d1);                                               \
      acc0_ = __builtin_amdgcn_mfma_f32_16x16x32_f16(fd_, as_hfrag(sQ[r][(4+g)^r]), acc0_,0,0,0);      \
      acc1_ = __builtin_amdgcn_mfma_f32_16x16x32_f16(fd_, as_hfrag(sQ[16+r][(4+g)^r]), acc1_,0,0,0); } \
    { f16x8 fd_ = as_hfrag(d2);                                               \
      acc0_ = __builtin_amdgcn_mfma_f32_16x16x32_f16(fd_, as_hfrag(sQ[r][(8+g)^r]), acc0_,0,0,0);      \
      acc1_ = __builtin_amdgcn_mfma_f32_16x16x32_f16(fd_, as_hfrag(sQ[16+r][(8+g)^r]), acc1_,0,0,0); } \
    { f16x8 fd_ = as_hfrag(d3);                                               \
      acc0_ = __builtin_amdgcn_mfma_f32_16x16x32_f16(fd_, as_hfrag(sQ[r][(12+g)^r]), acc0_,0,0,0);     \
      acc1_ = __builtin_amdgcn_mfma_f32_16x16x32_f16(fd_, as_hfrag(sQ[16+r][(12+g)^r]), acc1_,0,0,0); }\
    if ((sb) + g * 4 < RD) {                                                  \
        const int4 dt_ = sDtok4[((sb) >> 2) + g];                             \
        bank4_pk(acc0_, dt_, qt0, ks0, cnt0);                                 \
        bank4_pk(acc1_, dt_, qt1, ks1, cnt1);                                 \
    }                                                                         \
} while (0)

// ------------- kernel: fused-norm swapped-operand KNRM, spill-proof pipeline -------
// 1024 blocks (pair*b) x 256 thr (4 waves). 13 strips of 16 cols round-robin:
// wave w runs strips {w, w+4, w+8} (+strip 12 for w=0). mfma(A=D, B=Q):
// C row = dcol (g*4+j), C col = qrow (r); bank reads accumulators directly.
// Strip s+1 doc loads issued (named regs r0..r7) before strip s MFMA+bank.
__global__ __launch_bounds__(256, 4) void knrm_main(
    const float* __restrict__ emb, const float* __restrict__ W,
    const int* __restrict__ q1, const int* __restrict__ d1,
    const int* __restrict__ q2, const int* __restrict__ d2,
    float* __restrict__ logits)
{
    __shared__ int sQtok[32];
    __shared__ __align__(16) int sDtok[256];
    __shared__ int4 sQ[32][16];                    // 32 rows x 256B f16, swizzled
    __shared__ float kred[4][32][KN];              // 10752 B

    const int pb = blockIdx.x;
    const int pair = pb >> 9, b = pb & 511;
    const int* qind = (pair ? q2 : q1) + b * LQ;
    const int* dind = (pair ? d2 : d1) + b * RD;

    const int tid = threadIdx.x;
    const int lane = tid & 63, w = tid >> 6;
    const int r = lane & 15, g = lane >> 4;

    if (tid < 32) sQtok[tid] = (tid < LQ) ? qind[tid] : -2;
    // padded entries get clamped token; padded quads never reach the bank
    sDtok[tid] = dind[tid < RD ? tid : RD - 1];

    // ---- cooperative Q staging: row = tid>>3, 16 elems per thread ----
    {
        const int row = tid >> 3, seg = tid & 7;
        const int qi = qind[row < LQ ? row : LQ - 1];
        const float4* p = reinterpret_cast<const float4*>(emb + (size_t)qi * DIM + seg * 16);
        float4 v0 = p[0], v1 = p[1], v2 = p[2], v3 = p[3];
        float s0 = 0.f, s1 = 0.f, s2 = 0.f, s3 = 0.f;
        s0 = fmaf(v0.x, v0.x, fmaf(v0.y, v0.y, s0)); s1 = fmaf(v0.z, v0.z, fmaf(v0.w, v0.w, s1));
        s2 = fmaf(v1.x, v1.x, fmaf(v1.y, v1.y, s2)); s3 = fmaf(v1.z, v1.z, fmaf(v1.w, v1.w, s3));
        s0 = fmaf(v2.x, v2.x, fmaf(v2.y, v2.y, s0)); s1 = fmaf(v2.z, v2.z, fmaf(v2.w, v2.w, s1));
        s2 = fmaf(v3.x, v3.x, fmaf(v3.y, v3.y, s2)); s3 = fmaf(v3.z, v3.z, fmaf(v3.w, v3.w, s3));
        float ss = (s0 + s1) + (s2 + s3);
        ss += __shfl_xor(ss, 1);
        ss += __shfl_xor(ss, 2);
        ss += __shfl_xor(ss, 4);
        const float inv = rsqrtf(fmaxf(ss, 1e-24f));
        const __half2 h2 = __float2half2_rn(inv);
        int4 t0, t1;
        t0.x = (int)hscale(pk2h(v0.x, v0.y), h2);
        t0.y = (int)hscale(pk2h(v0.z, v0.w), h2);
        t0.z = (int)hscale(pk2h(v1.x, v1.y), h2);
        t0.w = (int)hscale(pk2h(v1.z, v1.w), h2);
        t1.x = (int)hscale(pk2h(v2.x, v2.y), h2);
        t1.y = (int)hscale(pk2h(v2.z, v2.w), h2);
        t1.z = (int)hscale(pk2h(v3.x, v3.y), h2);
        t1.w = (int)hscale(pk2h(v3.z, v3.w), h2);
        const int rw = row & 15;                   // XOR-swizzle (rule 21: both sides)
        sQ[row][(2 * seg) ^ rw]     = t0;
        sQ[row][(2 * seg + 1) ^ rw] = t1;
    }
    __syncthreads();                               // tokens + sQ ready (only barrier)

    const int qt0 = sQtok[r], qt1 = sQtok[16 + r];
    const int4* sDtok4 = (const int4*)sDtok;

    f32x2 ks0[10], ks1[10];
#pragma unroll
    for (int k = 0; k < 10; ++k) { ks0[k] = f32x2{0.f, 0.f}; ks1[k] = f32x2{0.f, 0.f}; }
    float cnt0 = 0.0f, cnt1 = 0.0f;

    // ---- pipelined strips: wave w -> {w, w+4, w+8} (+12 for w==0) ----
    {
        float4 r0, r1, r2, r3, r4, r5, r6, r7;     // in-flight raw row (named regs)
        int4 d0, d1, d2, d3;                       // packed f16 frags
        const int sb0 = w * 16, sb1 = sb0 + 64, sb2 = sb0 + 128;

        LOADROW(sb0);
        PACKROW();
        LOADROW(sb1);                              // prefetch strip 1
        DOSTRIP(sb0);
        PACKROW();
        LOADROW(sb2);                              // prefetch strip 2
        DOSTRIP(sb1);
        PACKROW();
        if (w == 0) LOADROW(192);                  // prefetch strip 12
        DOSTRIP(sb2);
        if (w == 0) {
            PACKROW();
            DOSTRIP(192);                          // cols 192..199 (quads g<2)
        }
    }

    // ---- reduce over g (xor16, xor32), writer lanes g==0 ----
#pragma unroll
    for (int k = 0; k < 10; ++k) {
        float a0 = ks0[k].x, b0 = ks0[k].y, a1 = ks1[k].x, b1 = ks1[k].y;
        a0 += __shfl_xor(a0, 16); a0 += __shfl_xor(a0, 32);
        b0 += __shfl_xor(b0, 16); b0 += __shfl_xor(b0, 32);
        a1 += __shfl_xor(a1, 16); a1 += __shfl_xor(a1, 32);
        b1 += __shfl_xor(b1, 16); b1 += __shfl_xor(b1, 32);
        ks0[k] = f32x2{a0, b0};
        ks1[k] = f32x2{a1, b1};
    }
    cnt0 += __shfl_xor(cnt0, 16); cnt0 += __shfl_xor(cnt0, 32);
    cnt1 += __shfl_xor(cnt1, 16); cnt1 += __shfl_xor(cnt1, 32);

    if (lane < 16) {
        float* k0 = &kred[w][r][0];
        float* k1 = &kred[w][16 + r][0];
#pragma unroll
        for (int k = 0; k < 10; ++k) {
            k0[k] = ks0[k].x;  k0[10 + k] = ks0[k].y;
            k1[k] = ks1[k].x;  k1[10 + k] = ks1[k].y;
        }
        k0[20] = cnt0;
        k1[20] = cnt1;
    }
    __syncthreads();

    // ---- in-block combine: B_j scale, log1p, W-dot, row reduce -> logit ----
    if (tid < 64) {
        float part = 0.0f;
        if (tid < LQ) {
#pragma unroll
            for (int k = 0; k < KN; ++k) {
                float s = kred[0][tid][k] + kred[1][tid][k]
                        + kred[2][tid][k] + kred[3][tid][k];
                float sc = 1.0f;
                if (k < 20) {
                    float j = (float)((k < 10) ? k : k - 10) - 4.5f;
                    sc = EXP2F(-0.721347520f * j * j);   // B_j (compile-time)
                }
                part += W[k] * log1pf(sc * s);
            }
        }
        part += __shfl_xor(part, 1);
        part += __shfl_xor(part, 2);
        part += __shfl_xor(part, 4);
        part += __shfl_xor(part, 8);
        part += __shfl_xor(part, 16);
        part += __shfl_xor(part, 32);
        if (tid == 0) logits[pair * BB + b] = part;   // bias cancels in diff
    }
}

// ------------- kernel 2: sigmoid of logit difference -------------
__global__ void knrm_final(const float* __restrict__ logits, float* __restrict__ out) {
    int i = blockIdx.x * blockDim.x + threadIdx.x;
    if (i < BB) {
        float x = logits[i] - logits[BB + i];
        out[i] = 1.0f / (1.0f + expf(-x));
    }
}

extern "C" void kernel_launch(void* const* d_in, const int* in_sizes, int n_in,
                              void* d_out, int out_size, void* d_ws, size_t ws_size,
                              hipStream_t stream) {
    const float* emb = (const float*)d_in[0];
    const float* W   = (const float*)d_in[1];
    const int* q1    = (const int*)d_in[3];
    const int* dd1   = (const int*)d_in[4];
    const int* q2    = (const int*)d_in[5];
    const int* dd2   = (const int*)d_in[6];

    float* logits = (float*)d_ws;                    // 1024 floats

    knrm_main<<<1024, 256, 0, stream>>>(emb, W, q1, dd1, q2, dd2, logits);
    knrm_final<<<2, 256, 0, stream>>>(logits, (float*)d_out);
}

// Round 17
// 38.820 us; speedup vs baseline: 1.3792x; 1.3248x over previous
//
#include <hip/hip_runtime.h>
#include <hip/hip_fp16.h>
#include <math.h>

#define V   50000
#define DIM 128
#define BB  512
#define LQ  30
#define RD  200
#define KN  21

typedef __attribute__((ext_vector_type(8))) _Float16 f16x8;  // 8 f16 = 4 VGPRs
typedef __attribute__((ext_vector_type(4))) float f32x4;
typedef __attribute__((ext_vector_type(2))) float f32x2;     // -> v_pk_*_f32

#if __has_builtin(__builtin_amdgcn_exp2f)
#define EXP2F(x) __builtin_amdgcn_exp2f(x)
#else
#define EXP2F(x) __expf((x) * 0.69314718f)
#endif

#define ALPHA 72.1347520f       // 50 * log2(e)
#define E10   22026.4657948f    // 2^(0.2*ALPHA) = e^10

static __device__ __forceinline__ f16x8 as_hfrag(int4 v) {
    return __builtin_bit_cast(f16x8, v);
}
static __device__ __forceinline__ unsigned pk2h(float a, float b) {
    return __builtin_bit_cast(unsigned, __builtin_amdgcn_cvt_pkrtz(a, b));
}
static __device__ __forceinline__ unsigned hscale(unsigned u, __half2 s) {
    return __builtin_bit_cast(unsigned, __hmul2(__builtin_bit_cast(__half2, u), s));
}

// Fused gather+normalize+f16-convert of one embedding row (doc side) — R13/R14
// proven sequential form. Lanes (r, g=0..3) jointly hold the row.
static __device__ __forceinline__ void gather_row_f16(const float* __restrict__ rowp,
                                                      int g, int4* f) {
    float c0 = 0.f, c1 = 0.f, c2 = 0.f, c3 = 0.f;
#pragma unroll
    for (int ks = 0; ks < 4; ++ks) {
        const float4* p = reinterpret_cast<const float4*>(rowp + ks * 32 + g * 8);
        float4 a = p[0], b = p[1];
        c0 = fmaf(a.x, a.x, fmaf(a.y, a.y, c0)); c1 = fmaf(a.z, a.z, fmaf(a.w, a.w, c1));
        c2 = fmaf(b.x, b.x, fmaf(b.y, b.y, c2)); c3 = fmaf(b.z, b.z, fmaf(b.w, b.w, c3));
        f[ks].x = (int)pk2h(a.x, a.y);
        f[ks].y = (int)pk2h(a.z, a.w);
        f[ks].z = (int)pk2h(b.x, b.y);
        f[ks].w = (int)pk2h(b.z, b.w);
    }
    float ss = (c0 + c1) + (c2 + c3);
    ss += __shfl_xor(ss, 16);
    ss += __shfl_xor(ss, 32);
    const float inv = rsqrtf(fmaxf(ss, 1e-24f));
    const __half2 h2 = __float2half2_rn(inv);
#pragma unroll
    for (int ks = 0; ks < 4; ++ks) {
        f[ks].x = (int)hscale((unsigned)f[ks].x, h2);
        f[ks].y = (int)hscale((unsigned)f[ks].y, h2);
        f[ks].z = (int)hscale((unsigned)f[ks].z, h2);
        f[ks].w = (int)hscale((unsigned)f[ks].w, h2);
    }
}

// Two-leg geometric Gaussian bank (verified R6..R14), packed f32x2
// (x = leg A, kernels 0..9 center mu=-0.5; y = leg B, 10..19 center +0.5),
// 4 independent t*u chains, tree summation. B_j folded in at the partial store.
// Exact kernel (mu=1, sigma=1e-3) = integer token equality count.
static __device__ __forceinline__ void bank4_pk(f32x4 pv, int4 dt, int qt,
                                                f32x2* ks2, float& cnt) {
    const float mv[4] = {pv[0], pv[1], pv[2], pv[3]};
    const int   dv[4] = {dt.x, dt.y, dt.z, dt.w};
    f32x2 t[4], u[4];
#pragma unroll
    for (int i = 0; i < 4; ++i) {
        float m  = mv[i];
        float dA = m + 0.5f, dB = m - 0.5f;
        float tA = EXP2F(-ALPHA * dA * (dA + 0.9f));   // leg A start (k=0)
        float tB = EXP2F(-ALPHA * dB * (dB + 0.9f));   // leg B start (k=10)
        float uB = EXP2F(14.4269504f * dB);            // 2^(0.2*ALPHA*dB)
        float uA = uB * E10;
        t[i] = f32x2{tA, tB};
        u[i] = f32x2{uA, uB};
        cnt += (dv[i] == qt) ? 1.0f : 0.0f;
    }
#pragma unroll
    for (int k = 0; k < 10; ++k) {
        ks2[k] += (t[0] + t[1]) + (t[2] + t[3]);       // tree: short dep chains
        t[0] *= u[0]; t[1] *= u[1]; t[2] *= u[2]; t[3] *= u[3];
    }
}

// ------------- kernel: R14 core, y-split into 2 col-halves for 2x TLP -------------
// grid (1024 pair*b, 2 halves) x 256 thr (4 waves). y=0: strips 0..6 (cols
// 0..111), y=1: strips 7..12 (cols 112..207). mfma(A=D_frag, B=Q_frag):
// C row = dcol (g*4+j), C col = qrow (r); bank reads accumulators directly.
// Q staged cooperatively once per block; partial sums -> global (plain stores).
__global__ __launch_bounds__(256, 4) void knrm_main(
    const float* __restrict__ emb,
    const int* __restrict__ q1, const int* __restrict__ d1,
    const int* __restrict__ q2, const int* __restrict__ d2,
    float* __restrict__ partial)
{
    __shared__ int sQtok[32];
    __shared__ __align__(16) int sDtok[256];
    __shared__ int4 sQ[32][16];                    // 32 rows x 256B f16, swizzled
    __shared__ float kred[4][32][KN];              // 10752 B

    const int pb = blockIdx.x, y = blockIdx.y;
    const int pair = pb >> 9, b = pb & 511;
    const int* qind = (pair ? q2 : q1) + b * LQ;
    const int* dind = (pair ? d2 : d1) + b * RD;

    const int tid = threadIdx.x;
    const int lane = tid & 63, w = tid >> 6;
    const int r = lane & 15, g = lane >> 4;

    if (tid < 32) sQtok[tid] = (tid < LQ) ? qind[tid] : -2;
    // padded entries get clamped token; padded quads never reach the bank
    sDtok[tid] = dind[tid < RD ? tid : RD - 1];

    // ---- cooperative Q staging: row = tid>>3, 16 elems per thread ----
    {
        const int row = tid >> 3, seg = tid & 7;
        const int qi = qind[row < LQ ? row : LQ - 1];
        const float4* p = reinterpret_cast<const float4*>(emb + (size_t)qi * DIM + seg * 16);
        float4 v0 = p[0], v1 = p[1], v2 = p[2], v3 = p[3];
        float s0 = 0.f, s1 = 0.f, s2 = 0.f, s3 = 0.f;
        s0 = fmaf(v0.x, v0.x, fmaf(v0.y, v0.y, s0)); s1 = fmaf(v0.z, v0.z, fmaf(v0.w, v0.w, s1));
        s2 = fmaf(v1.x, v1.x, fmaf(v1.y, v1.y, s2)); s3 = fmaf(v1.z, v1.z, fmaf(v1.w, v1.w, s3));
        s0 = fmaf(v2.x, v2.x, fmaf(v2.y, v2.y, s0)); s1 = fmaf(v2.z, v2.z, fmaf(v2.w, v2.w, s1));
        s2 = fmaf(v3.x, v3.x, fmaf(v3.y, v3.y, s2)); s3 = fmaf(v3.z, v3.z, fmaf(v3.w, v3.w, s3));
        float ss = (s0 + s1) + (s2 + s3);
        ss += __shfl_xor(ss, 1);
        ss += __shfl_xor(ss, 2);
        ss += __shfl_xor(ss, 4);
        const float inv = rsqrtf(fmaxf(ss, 1e-24f));
        const __half2 h2 = __float2half2_rn(inv);
        int4 t0, t1;
        t0.x = (int)hscale(pk2h(v0.x, v0.y), h2);
        t0.y = (int)hscale(pk2h(v0.z, v0.w), h2);
        t0.z = (int)hscale(pk2h(v1.x, v1.y), h2);
        t0.w = (int)hscale(pk2h(v1.z, v1.w), h2);
        t1.x = (int)hscale(pk2h(v2.x, v2.y), h2);
        t1.y = (int)hscale(pk2h(v2.z, v2.w), h2);
        t1.z = (int)hscale(pk2h(v3.x, v3.y), h2);
        t1.w = (int)hscale(pk2h(v3.z, v3.w), h2);
        const int rw = row & 15;                   // XOR-swizzle (rule 21: both sides)
        sQ[row][(2 * seg) ^ rw]     = t0;
        sQ[row][(2 * seg + 1) ^ rw] = t1;
    }
    __syncthreads();                               // tokens + sQ ready (only barrier)

    // ---- Q frags held in regs (R14-proven; NOT re-read per strip) ----
    int4 qa[4], qb[4];
#pragma unroll
    for (int ks = 0; ks < 4; ++ks) {
        qa[ks] = sQ[r][(ks * 4 + g) ^ r];
        qb[ks] = sQ[16 + r][(ks * 4 + g) ^ r];
    }
    const int qt0 = sQtok[r], qt1 = sQtok[16 + r];
    const int4* sDtok4 = (const int4*)sDtok;

    f32x2 ks0[10], ks1[10];
#pragma unroll
    for (int k = 0; k < 10; ++k) { ks0[k] = f32x2{0.f, 0.f}; ks1[k] = f32x2{0.f, 0.f}; }
    float cnt0 = 0.0f, cnt1 = 0.0f;

    auto strip = [&](int sbase) {
        const int di = sDtok[sbase + r];
        int4 df[4];
        gather_row_f16(emb + (size_t)di * DIM, g, df);
        f32x4 acc0 = {0.f, 0.f, 0.f, 0.f}, acc1 = {0.f, 0.f, 0.f, 0.f};
#pragma unroll
        for (int ks = 0; ks < 4; ++ks) {
            f16x8 fd = as_hfrag(df[ks]);
            acc0 = __builtin_amdgcn_mfma_f32_16x16x32_f16(fd, as_hfrag(qa[ks]), acc0, 0, 0, 0);
            acc1 = __builtin_amdgcn_mfma_f32_16x16x32_f16(fd, as_hfrag(qb[ks]), acc1, 0, 0, 0);
        }
        // acc element j <-> dcol = sbase + g*4 + j ; qrow = r (+16 for acc1)
        if (sbase + g * 4 < RD) {                  // RD%4==0 -> quad all-or-none
            const int4 dt = sDtok4[(sbase >> 2) + g];
            bank4_pk(acc0, dt, qt0, ks0, cnt0);
            bank4_pk(acc1, dt, qt1, ks1, cnt1);
        }
    };

    // ---- strip schedule: y=0 -> {w*32, w*32+16 (w<3), 96}; y=1 -> 112..192 ----
    if (y == 0) {
        if (w < 3) { strip(w * 32); strip(w * 32 + 16); }
        else       { strip(96); }
    } else {
        if (w < 2) { strip(112 + w * 32); strip(128 + w * 32); }
        else       { strip(176 + (w - 2) * 16); }   // 176, 192 (192: quads g<2)
    }

    // ---- reduce over g (xor16, xor32), writer lanes g==0 ----
#pragma unroll
    for (int k = 0; k < 10; ++k) {
        float a0 = ks0[k].x, b0 = ks0[k].y, a1 = ks1[k].x, b1 = ks1[k].y;
        a0 += __shfl_xor(a0, 16); a0 += __shfl_xor(a0, 32);
        b0 += __shfl_xor(b0, 16); b0 += __shfl_xor(b0, 32);
        a1 += __shfl_xor(a1, 16); a1 += __shfl_xor(a1, 32);
        b1 += __shfl_xor(b1, 16); b1 += __shfl_xor(b1, 32);
        ks0[k] = f32x2{a0, b0};
        ks1[k] = f32x2{a1, b1};
    }
    cnt0 += __shfl_xor(cnt0, 16); cnt0 += __shfl_xor(cnt0, 32);
    cnt1 += __shfl_xor(cnt1, 16); cnt1 += __shfl_xor(cnt1, 32);

    if (lane < 16) {
        float* k0 = &kred[w][r][0];
        float* k1 = &kred[w][16 + r][0];
#pragma unroll
        for (int k = 0; k < 10; ++k) {
            k0[k] = ks0[k].x;  k0[10 + k] = ks0[k].y;
            k1[k] = ks1[k].x;  k1[10 + k] = ks1[k].y;
        }
        k0[20] = cnt0;
        k1[20] = cnt1;
    }
    __syncthreads();

    // ---- partial store (plain indexed stores, B_j folded in) ----
    float* dst = partial + ((size_t)pb * 2 + y) * (LQ * KN);
    for (int e = tid; e < LQ * KN; e += 256) {
        int row = e / KN, k = e - row * KN;
        float s = kred[0][row][k] + kred[1][row][k]
                + kred[2][row][k] + kred[3][row][k];
        float sc = 1.0f;
        if (k < 20) {
            float j = (float)((k < 10) ? k : k - 10) - 4.5f;
            sc = EXP2F(-0.721347520f * j * j);     // B_j = 2^(-0.01*ALPHA*j^2)
        }
        dst[e] = sc * s;
    }
}

// ------------- kernel 2: combine halves, log1p, W-dot, diff, sigmoid -------------
__global__ __launch_bounds__(128) void knrm_finish(const float* __restrict__ partial,
                                                   const float* __restrict__ W,
                                                   float* __restrict__ out) {
    __shared__ float red[2];
    const int b = blockIdx.x, tid = threadIdx.x;
    const float* p1 = partial + (size_t)(b * 2) * (LQ * KN);
    const float* p2 = partial + (size_t)((BB + b) * 2) * (LQ * KN);
    float s = 0.0f;
    for (int e = tid; e < LQ * KN; e += 128) {
        int row = e / KN, k = e - row * KN;
        float s1 = p1[e] + p1[LQ * KN + e];
        float s2 = p2[e] + p2[LQ * KN + e];
        s += W[k] * (log1pf(s1) - log1pf(s2));
    }
#pragma unroll
    for (int off = 1; off < 64; off <<= 1) s += __shfl_xor(s, off);
    if ((tid & 63) == 0) red[tid >> 6] = s;
    __syncthreads();
    if (tid == 0) {
        float logit = red[0] + red[1];   // bias cancels in the difference
        out[b] = 1.0f / (1.0f + expf(-logit));
    }
}

extern "C" void kernel_launch(void* const* d_in, const int* in_sizes, int n_in,
                              void* d_out, int out_size, void* d_ws, size_t ws_size,
                              hipStream_t stream) {
    const float* emb = (const float*)d_in[0];
    const float* W   = (const float*)d_in[1];
    const int* q1    = (const int*)d_in[3];
    const int* dd1   = (const int*)d_in[4];
    const int* q2    = (const int*)d_in[5];
    const int* dd2   = (const int*)d_in[6];

    float* partial = (float*)d_ws;                   // 2048*630 f32 = 5.16 MB

    dim3 grid(1024, 2);
    knrm_main<<<grid, 256, 0, stream>>>(emb, q1, dd1, q2, dd2, partial);
    knrm_finish<<<BB, 128, 0, stream>>>(partial, W, (float*)d_out);
}

// Round 18
// 33.765 us; speedup vs baseline: 1.5856x; 1.1497x over previous
//
#include <hip/hip_runtime.h>
#include <hip/hip_fp16.h>
#include <math.h>

#define V   50000
#define DIM 128
#define BB  512
#define LQ  30
#define RD  200
#define KN  21

typedef __attribute__((ext_vector_type(8))) _Float16 f16x8;  // 8 f16 = 4 VGPRs
typedef __attribute__((ext_vector_type(4))) float f32x4;
typedef __attribute__((ext_vector_type(2))) float f32x2;     // -> v_pk_*_f32

#if __has_builtin(__builtin_amdgcn_exp2f)
#define EXP2F(x) __builtin_amdgcn_exp2f(x)
#else
#define EXP2F(x) __expf((x) * 0.69314718f)
#endif

#define ALPHA 72.1347520f       // 50 * log2(e)
#define E10   22026.4657948f    // 2^(0.2*ALPHA) = e^10

static __device__ __forceinline__ f16x8 as_hfrag(int4 v) {
    return __builtin_bit_cast(f16x8, v);
}
static __device__ __forceinline__ unsigned pk2h(float a, float b) {
    return __builtin_bit_cast(unsigned, __builtin_amdgcn_cvt_pkrtz(a, b));
}
static __device__ __forceinline__ unsigned hscale(unsigned u, __half2 s) {
    return __builtin_bit_cast(unsigned, __hmul2(__builtin_bit_cast(__half2, u), s));
}

// Fused gather+normalize+f16-convert of one embedding row (doc side).
// Lanes (r, g=0..3) jointly hold the row; lane slice = elements ks*32+g*8..+7.
// ss reduced across g via shfl_xor 16/32. RTZ-pack first, then f16 scale.
static __device__ __forceinline__ void gather_row_f16(const float* __restrict__ rowp,
                                                      int g, int4* f) {
    float ss = 0.0f;
#pragma unroll
    for (int ks = 0; ks < 4; ++ks) {
        const float4* p = reinterpret_cast<const float4*>(rowp + ks * 32 + g * 8);
        float4 a = p[0], b = p[1];
        ss = fmaf(a.x, a.x, fmaf(a.y, a.y, fmaf(a.z, a.z, fmaf(a.w, a.w, ss))));
        ss = fmaf(b.x, b.x, fmaf(b.y, b.y, fmaf(b.z, b.z, fmaf(b.w, b.w, ss))));
        f[ks].x = (int)pk2h(a.x, a.y);
        f[ks].y = (int)pk2h(a.z, a.w);
        f[ks].z = (int)pk2h(b.x, b.y);
        f[ks].w = (int)pk2h(b.z, b.w);
    }
    ss += __shfl_xor(ss, 16);
    ss += __shfl_xor(ss, 32);
    const float inv = rsqrtf(fmaxf(ss, 1e-24f));
    const __half2 h2 = __float2half2_rn(inv);
#pragma unroll
    for (int ks = 0; ks < 4; ++ks) {
        f[ks].x = (int)hscale((unsigned)f[ks].x, h2);
        f[ks].y = (int)hscale((unsigned)f[ks].y, h2);
        f[ks].z = (int)hscale((unsigned)f[ks].z, h2);
        f[ks].w = (int)hscale((unsigned)f[ks].w, h2);
    }
}

// Two-leg geometric Gaussian bank (verified R6..R14), packed f32x2
// (x = leg A, kernels 0..9 center mu=-0.5; y = leg B, 10..19 center +0.5),
// 4 independent t*u chains, tree summation. B_j folded in at combine.
// Exact kernel (mu=1, sigma=1e-3) = integer token equality count.
static __device__ __forceinline__ void bank4_pk(f32x4 pv, int4 dt, int qt,
                                                f32x2* ks2, float& cnt) {
    const float mv[4] = {pv[0], pv[1], pv[2], pv[3]};
    const int   dv[4] = {dt.x, dt.y, dt.z, dt.w};
    f32x2 t[4], u[4];
#pragma unroll
    for (int i = 0; i < 4; ++i) {
        float m  = mv[i];
        float dA = m + 0.5f, dB = m - 0.5f;
        float tA = EXP2F(-ALPHA * dA * (dA + 0.9f));   // leg A start (k=0)
        float tB = EXP2F(-ALPHA * dB * (dB + 0.9f));   // leg B start (k=10)
        float uB = EXP2F(14.4269504f * dB);            // 2^(0.2*ALPHA*dB)
        float uA = uB * E10;
        t[i] = f32x2{tA, tB};
        u[i] = f32x2{uA, uB};
        cnt += (dv[i] == qt) ? 1.0f : 0.0f;
    }
#pragma unroll
    for (int k = 0; k < 10; ++k) {
        ks2[k] += (t[0] + t[1]) + (t[2] + t[3]);       // tree: short dep chains
        t[0] *= u[0]; t[1] *= u[1]; t[2] *= u[2]; t[3] *= u[3];
    }
}

// ------------- kernel: fused-norm swapped-operand KNRM, cooperative Q staging -------
// 1024 blocks (pair*b) x 256 thr (4 waves). Wave w owns doc cols w*64..+63
// (4 strips of 16; wave 3: 1 strip). mfma(A=D_frag, B=Q_frag): C row = dcol
// (g*4+j), C col = qrow (r) -> bank consumes accumulators from registers.
// Q rows normalized ONCE per block into an XOR-swizzled 8KB LDS f16 tile.
// Doc rows fused-gathered per strip. In-block combine -> logit.
__global__ __launch_bounds__(256, 4) void knrm_main(
    const float* __restrict__ emb, const float* __restrict__ W,
    const int* __restrict__ q1, const int* __restrict__ d1,
    const int* __restrict__ q2, const int* __restrict__ d2,
    float* __restrict__ logits)
{
    __shared__ int sQtok[32];
    __shared__ __align__(16) int sDtok[256];
    __shared__ int4 sQ[32][16];                    // 32 rows x 256B f16, swizzled
    __shared__ float kred[4][32][KN];              // 10752 B

    const int pb = blockIdx.x;
    const int pair = pb >> 9, b = pb & 511;
    const int* qind = (pair ? q2 : q1) + b * LQ;
    const int* dind = (pair ? d2 : d1) + b * RD;

    const int tid = threadIdx.x;
    const int lane = tid & 63, w = tid >> 6;
    const int r = lane & 15, g = lane >> 4;

    if (tid < 32) sQtok[tid] = (tid < LQ) ? qind[tid] : -2;
    // padded entries get clamped token; padded quads never reach the bank
    sDtok[tid] = dind[tid < RD ? tid : RD - 1];

    // ---- cooperative Q staging: row = tid>>3, 16 elems per thread ----
    {
        const int row = tid >> 3, seg = tid & 7;
        const int qi = qind[row < LQ ? row : LQ - 1];
        const float4* p = reinterpret_cast<const float4*>(emb + (size_t)qi * DIM + seg * 16);
        float4 v0 = p[0], v1 = p[1], v2 = p[2], v3 = p[3];
        float s0 = 0.f, s1 = 0.f, s2 = 0.f, s3 = 0.f;
        s0 = fmaf(v0.x, v0.x, fmaf(v0.y, v0.y, s0)); s1 = fmaf(v0.z, v0.z, fmaf(v0.w, v0.w, s1));
        s2 = fmaf(v1.x, v1.x, fmaf(v1.y, v1.y, s2)); s3 = fmaf(v1.z, v1.z, fmaf(v1.w, v1.w, s3));
        s0 = fmaf(v2.x, v2.x, fmaf(v2.y, v2.y, s0)); s1 = fmaf(v2.z, v2.z, fmaf(v2.w, v2.w, s1));
        s2 = fmaf(v3.x, v3.x, fmaf(v3.y, v3.y, s2)); s3 = fmaf(v3.z, v3.z, fmaf(v3.w, v3.w, s3));
        float ss = (s0 + s1) + (s2 + s3);
        ss += __shfl_xor(ss, 1);
        ss += __shfl_xor(ss, 2);
        ss += __shfl_xor(ss, 4);
        const float inv = rsqrtf(fmaxf(ss, 1e-24f));
        int4 t0, t1;
        t0.x = (int)pk2h(v0.x * inv, v0.y * inv);
        t0.y = (int)pk2h(v0.z * inv, v0.w * inv);
        t0.z = (int)pk2h(v1.x * inv, v1.y * inv);
        t0.w = (int)pk2h(v1.z * inv, v1.w * inv);
        t1.x = (int)pk2h(v2.x * inv, v2.y * inv);
        t1.y = (int)pk2h(v2.z * inv, v2.w * inv);
        t1.z = (int)pk2h(v3.x * inv, v3.y * inv);
        t1.w = (int)pk2h(v3.z * inv, v3.w * inv);
        const int rw = row & 15;                   // XOR-swizzle (rule 21: both sides)
        sQ[row][(2 * seg) ^ rw]     = t0;
        sQ[row][(2 * seg + 1) ^ rw] = t1;
    }
    __syncthreads();                               // tokens + sQ ready (only barrier)

    // ---- Q frags from LDS (swizzled read, conflict-free) ----
    int4 qa[4], qb[4];
#pragma unroll
    for (int ks = 0; ks < 4; ++ks) {
        qa[ks] = sQ[r][(ks * 4 + g) ^ r];
        qb[ks] = sQ[16 + r][(ks * 4 + g) ^ r];
    }
    const int qt0 = sQtok[r], qt1 = sQtok[16 + r];
    const int4* sDtok4 = (const int4*)sDtok;

    f32x2 ks0[10], ks1[10];
#pragma unroll
    for (int k = 0; k < 10; ++k) { ks0[k] = f32x2{0.f, 0.f}; ks1[k] = f32x2{0.f, 0.f}; }
    float cnt0 = 0.0f, cnt1 = 0.0f;

    auto strip = [&](int sbase) {
        const int di = sDtok[sbase + r];
        int4 df[4];
        gather_row_f16(emb + (size_t)di * DIM, g, df);
        f32x4 acc0 = {0.f, 0.f, 0.f, 0.f}, acc1 = {0.f, 0.f, 0.f, 0.f};
#pragma unroll
        for (int ks = 0; ks < 4; ++ks) {
            f16x8 fd = as_hfrag(df[ks]);
            acc0 = __builtin_amdgcn_mfma_f32_16x16x32_f16(fd, as_hfrag(qa[ks]), acc0, 0, 0, 0);
            acc1 = __builtin_amdgcn_mfma_f32_16x16x32_f16(fd, as_hfrag(qb[ks]), acc1, 0, 0, 0);
        }
        // acc element j <-> dcol = sbase + g*4 + j ; qrow = r (+16 for acc1)
        if (sbase + g * 4 < RD) {                  // RD%4==0 -> quad all-or-none
            const int4 dt = sDtok4[(sbase >> 2) + g];
            bank4_pk(acc0, dt, qt0, ks0, cnt0);
            bank4_pk(acc1, dt, qt1, ks1, cnt1);
        }
    };

    if (w < 3) {
#pragma unroll 2
        for (int s = 0; s < 4; ++s) strip(w * 64 + s * 16);
    } else {
        strip(192);
    }

    // ---- reduce over g (xor16, xor32), writer lanes g==0 ----
#pragma unroll
    for (int k = 0; k < 10; ++k) {
        float a0 = ks0[k].x, b0 = ks0[k].y, a1 = ks1[k].x, b1 = ks1[k].y;
        a0 += __shfl_xor(a0, 16); a0 += __shfl_xor(a0, 32);
        b0 += __shfl_xor(b0, 16); b0 += __shfl_xor(b0, 32);
        a1 += __shfl_xor(a1, 16); a1 += __shfl_xor(a1, 32);
        b1 += __shfl_xor(b1, 16); b1 += __shfl_xor(b1, 32);
        ks0[k] = f32x2{a0, b0};
        ks1[k] = f32x2{a1, b1};
    }
    cnt0 += __shfl_xor(cnt0, 16); cnt0 += __shfl_xor(cnt0, 32);
    cnt1 += __shfl_xor(cnt1, 16); cnt1 += __shfl_xor(cnt1, 32);

    if (lane < 16) {
        float* k0 = &kred[w][r][0];
        float* k1 = &kred[w][16 + r][0];
#pragma unroll
        for (int k = 0; k < 10; ++k) {
            k0[k] = ks0[k].x;  k0[10 + k] = ks0[k].y;
            k1[k] = ks1[k].x;  k1[10 + k] = ks1[k].y;
        }
        k0[20] = cnt0;
        k1[20] = cnt1;
    }
    __syncthreads();

    // ---- in-block combine: B_j scale, log1p, W-dot, row reduce -> logit ----
    if (tid < 64) {
        float part = 0.0f;
        if (tid < LQ) {
#pragma unroll
            for (int k = 0; k < KN; ++k) {
                float s = kred[0][tid][k] + kred[1][tid][k]
                        + kred[2][tid][k] + kred[3][tid][k];
                float sc = 1.0f;
                if (k < 20) {
                    float j = (float)((k < 10) ? k : k - 10) - 4.5f;
                    sc = EXP2F(-0.721347520f * j * j);   // B_j (compile-time)
                }
                part += W[k] * log1pf(sc * s);
            }
        }
        part += __shfl_xor(part, 1);
        part += __shfl_xor(part, 2);
        part += __shfl_xor(part, 4);
        part += __shfl_xor(part, 8);
        part += __shfl_xor(part, 16);
        part += __shfl_xor(part, 32);
        if (tid == 0) logits[pair * BB + b] = part;   // bias cancels in diff
    }
}

// ------------- kernel 2: sigmoid of logit difference -------------
__global__ void knrm_final(const float* __restrict__ logits, float* __restrict__ out) {
    int i = blockIdx.x * blockDim.x + threadIdx.x;
    if (i < BB) {
        float x = logits[i] - logits[BB + i];
        out[i] = 1.0f / (1.0f + expf(-x));
    }
}

extern "C" void kernel_launch(void* const* d_in, const int* in_sizes, int n_in,
                              void* d_out, int out_size, void* d_ws, size_t ws_size,
                              hipStream_t stream) {
    const float* emb = (const float*)d_in[0];
    const float* W   = (const float*)d_in[1];
    const int* q1    = (const int*)d_in[3];
    const int* dd1   = (const int*)d_in[4];
    const int* q2    = (const int*)d_in[5];
    const int* dd2   = (const int*)d_in[6];

    float* logits = (float*)d_ws;                    // 1024 floats

    knrm_main<<<1024, 256, 0, stream>>>(emb, W, q1, dd1, q2, dd2, logits);
    knrm_final<<<2, 256, 0, stream>>>(logits, (float*)d_out);
}